// Round 1
// baseline (261.886 us; speedup 1.0000x reference)
//
#include <hip/hip_runtime.h>
#include <stdint.h>

// Problem dims
#define T_HRZ 1024
#define NBAT  128
#define NHID  256
#define NPAIR 128
#define NUIN  64
#define NYOUT 64
#define LCH   16   // chunk length
#define CCH   64   // number of chunks (LCH*CCH == T_HRZ)

// Workspace layout (float offsets). Total = 21,037,568 floats = 84.2 MB.
#define WS_LAM   0         // lr[128], li[128]
#define WS_LAML  256       // (lambda^L) r[128], i[128]
#define WS_X0P   512       // x0 pair-interleaved [b][j][2] : 128*128*2
#define WS_BNFT  33280     // BnfT[u][h] = B[h][u]*nf[h] : 64*256
#define WS_WT    49664     // WT[h][i] = W_x2y[i][h] : 256*64
#define WS_S     66048     // chunk sums  [c][b][j] float2 : 64*128*128*2
#define WS_E     2163200   // entry states [c][b][j] float2 : 64*128*128*2
#define WS_BU    4260352   // Bu packed bf16 pairs (u32) [t][b][j] : 1024*128*128

__device__ __forceinline__ unsigned int f2bf_bits(float x) {
  unsigned int u = __float_as_uint(x);
  return (u + 0x7fffu + ((u >> 16) & 1u)) >> 16;  // RNE
}

// ---------------------------------------------------------------------------
// K1: prep. grid 130 x 256 threads.
//   blocks 0..127: x0[b] = y0[b] @ W_y2x^T + b_y2x (pair-interleaved store)
//   block 128    : lambda, lambda^L, BnfT
//   block 129    : WT (transpose of W_x2y)
// ---------------------------------------------------------------------------
__global__ __launch_bounds__(256) void k_prep(
    const float* __restrict__ y0, const float* __restrict__ lrc,
    const float* __restrict__ lic, const float* __restrict__ Bm,
    const float* __restrict__ Wy2x, const float* __restrict__ by2x,
    const float* __restrict__ Wx2y, float* __restrict__ ws)
{
  int b = blockIdx.x;
  int h = threadIdx.x;  // 0..255
  if (b < NBAT) {
    __shared__ float y0s[NYOUT];
    if (h < NYOUT) y0s[h] = y0[b * NYOUT + h];
    __syncthreads();
    float acc = by2x[h];
    const float* wr = Wy2x + h * NYOUT;
#pragma unroll 16
    for (int k = 0; k < NYOUT; ++k) acc += y0s[k] * wr[k];
    int j = h & (NPAIR - 1);
    int comp = h >> 7;
    ws[WS_X0P + (b * NPAIR + j) * 2 + comp] = acc;
  } else if (b == NBAT) {
    if (h < NPAIR) {
      float a  = fabsf(lrc[h]);
      float r  = expf(-a);
      float th = 1.5707963267948966f * lic[h];
      float lr = r * cosf(th);
      float li = r * sinf(th);
      ws[WS_LAM + h]          = lr;
      ws[WS_LAM + NPAIR + h]  = li;
      float pr = 1.f, pi = 0.f;
      for (int it = 0; it < LCH; ++it) {
        float nr = pr * lr - pi * li;
        float ni = pr * li + pi * lr;
        pr = nr; pi = ni;
      }
      ws[WS_LAML + h]         = pr;
      ws[WS_LAML + NPAIR + h] = pi;
    }
    float a2 = fabsf(lrc[h & (NPAIR - 1)]);
    float nf = sqrtf(1.f - expf(-2.f * a2));
    for (int u = 0; u < NUIN; ++u)
      ws[WS_BNFT + u * NHID + h] = Bm[h * NUIN + u] * nf;
  } else {
    for (int i = 0; i < NYOUT; ++i)
      ws[WS_WT + h * NYOUT + i] = Wx2y[i * NHID + h];
  }
}

// ---------------------------------------------------------------------------
// K2: phase A. grid (CCH, NBAT) x 128 threads. Thread j = pair j.
// Computes Bu tile (16 x 256) via register-tiled GEMM, writes Bu (bf16 pairs),
// and the chunk summary s[c] via in-register scan from zero state.
// ---------------------------------------------------------------------------
__global__ __launch_bounds__(128) void k_phaseA(
    const float* __restrict__ U, float* __restrict__ ws)
{
  int c = blockIdx.x, b = blockIdx.y;
  int j = threadIdx.x;  // pair index 0..127
  __shared__ float uT[NUIN * 20];  // [u][l] padded to 20 (16B-aligned rows)

  // Stage U tile transposed: two fully-coalesced float4 loads per thread.
#pragma unroll
  for (int p = 0; p < 2; ++p) {
    int idx = p * 128 + j;          // 0..255 -> group of 4 elements
    int l   = idx >> 4;             // t within chunk
    int u0  = (idx & 15) * 4;
    const float4 v = *(const float4*)(U + ((size_t)(c * LCH + l) * NBAT + b) * NUIN + u0);
    uT[(u0 + 0) * 20 + l] = v.x;
    uT[(u0 + 1) * 20 + l] = v.y;
    uT[(u0 + 2) * 20 + l] = v.z;
    uT[(u0 + 3) * 20 + l] = v.w;
  }
  __syncthreads();

  float bu1[LCH], bu2[LCH];
#pragma unroll
  for (int l = 0; l < LCH; ++l) { bu1[l] = 0.f; bu2[l] = 0.f; }

  const float* bnft = ws + WS_BNFT;
#pragma unroll 2
  for (int u = 0; u < NUIN; ++u) {
    float br1 = bnft[u * NHID + j];
    float br2 = bnft[u * NHID + NPAIR + j];
    const float4* uq = (const float4*)(uT + u * 20);
    float4 v0 = uq[0], v1 = uq[1], v2 = uq[2], v3 = uq[3];
    bu1[0]  += br1 * v0.x; bu2[0]  += br2 * v0.x;
    bu1[1]  += br1 * v0.y; bu2[1]  += br2 * v0.y;
    bu1[2]  += br1 * v0.z; bu2[2]  += br2 * v0.z;
    bu1[3]  += br1 * v0.w; bu2[3]  += br2 * v0.w;
    bu1[4]  += br1 * v1.x; bu2[4]  += br2 * v1.x;
    bu1[5]  += br1 * v1.y; bu2[5]  += br2 * v1.y;
    bu1[6]  += br1 * v1.z; bu2[6]  += br2 * v1.z;
    bu1[7]  += br1 * v1.w; bu2[7]  += br2 * v1.w;
    bu1[8]  += br1 * v2.x; bu2[8]  += br2 * v2.x;
    bu1[9]  += br1 * v2.y; bu2[9]  += br2 * v2.y;
    bu1[10] += br1 * v2.z; bu2[10] += br2 * v2.z;
    bu1[11] += br1 * v2.w; bu2[11] += br2 * v2.w;
    bu1[12] += br1 * v3.x; bu2[12] += br2 * v3.x;
    bu1[13] += br1 * v3.y; bu2[13] += br2 * v3.y;
    bu1[14] += br1 * v3.z; bu2[14] += br2 * v3.z;
    bu1[15] += br1 * v3.w; bu2[15] += br2 * v3.w;
  }

  float lr = ws[WS_LAM + j], li = ws[WS_LAM + NPAIR + j];
  float s1 = 0.f, s2 = 0.f;
  unsigned int* bu_out = (unsigned int*)(ws + WS_BU);
#pragma unroll
  for (int l = 0; l < LCH; ++l) {
    float v1f = bu1[l], v2f = bu2[l];
    bu_out[((size_t)(c * LCH + l) * NBAT + b) * NPAIR + j] =
        f2bf_bits(v1f) | (f2bf_bits(v2f) << 16);
    float n1 = lr * s1 - li * s2 + v1f;
    float n2 = li * s1 + lr * s2 + v2f;
    s1 = n1; s2 = n2;
  }
  float2* sp = (float2*)(ws + WS_S);
  sp[((size_t)c * NBAT + b) * NPAIR + j] = make_float2(s1, s2);
}

// ---------------------------------------------------------------------------
// K3: phase B. grid NBAT x 128 threads. Scan over chunk summaries -> entry
// states e[c] (e[0] = x0; e[c] = Lambda^L * e[c-1] + s[c-1]).
// ---------------------------------------------------------------------------
__global__ __launch_bounds__(128) void k_phaseB(float* __restrict__ ws)
{
  int b = blockIdx.x, j = threadIdx.x;
  float e1 = ws[WS_X0P + (b * NPAIR + j) * 2 + 0];
  float e2 = ws[WS_X0P + (b * NPAIR + j) * 2 + 1];
  float Lr = ws[WS_LAML + j], Li = ws[WS_LAML + NPAIR + j];
  float2* sp = (float2*)(ws + WS_S);
  float2* ep = (float2*)(ws + WS_E);
  for (int c = 0; c < CCH; ++c) {
    size_t o = ((size_t)c * NBAT + b) * NPAIR + j;
    ep[o] = make_float2(e1, e2);
    float2 s = sp[o];
    float n1 = Lr * e1 - Li * e2 + s.x;
    float n2 = Li * e1 + Lr * e2 + s.y;
    e1 = n1; e2 = n2;
  }
}

// ---------------------------------------------------------------------------
// K4: phase C. grid (CCH, NBAT) x 128 threads.
// Replays the 16-step scan from e[c] (Bu bf16 loads), stages X tile in LDS,
// then Y = X @ W_x2y^T register-tiled over the 16 t values, 4-way reduce.
// ---------------------------------------------------------------------------
__global__ __launch_bounds__(128) void k_phaseC(
    const float* __restrict__ bx2y, float* __restrict__ out,
    float* __restrict__ ws)
{
  int c = blockIdx.x, b = blockIdx.y;
  int j = threadIdx.x;
  __shared__ float xT[NHID * 20];           // [h][l] padded to 20
  __shared__ float part[4 * LCH * NYOUT];   // [g4][l][y]

  float lr = ws[WS_LAM + j], li = ws[WS_LAM + NPAIR + j];
  float2 e = ((float2*)(ws + WS_E))[((size_t)c * NBAT + b) * NPAIR + j];
  float x1 = e.x, x2 = e.y;
  const unsigned int* bu_in = (const unsigned int*)(ws + WS_BU);
#pragma unroll
  for (int l = 0; l < LCH; ++l) {
    unsigned int pk = bu_in[((size_t)(c * LCH + l) * NBAT + b) * NPAIR + j];
    float b1 = __uint_as_float(pk << 16);
    float b2 = __uint_as_float(pk & 0xffff0000u);
    float n1 = lr * x1 - li * x2 + b1;
    float n2 = li * x1 + lr * x2 + b2;
    x1 = n1; x2 = n2;
    xT[j * 20 + l]           = x1;
    xT[(NPAIR + j) * 20 + l] = x2;
  }
  __syncthreads();

  int i  = j & 31;
  int g4 = j >> 5;
  float acc0[LCH], acc1[LCH];
#pragma unroll
  for (int l = 0; l < LCH; ++l) { acc0[l] = 0.f; acc1[l] = 0.f; }

  const float* wt = ws + WS_WT;
#pragma unroll 2
  for (int k = 0; k < 64; ++k) {
    int h = g4 * 64 + k;
    float w0 = wt[h * NYOUT + i];
    float w1 = wt[h * NYOUT + 32 + i];
    const float4* xq = (const float4*)(xT + h * 20);
    float4 v0 = xq[0], v1 = xq[1], v2 = xq[2], v3 = xq[3];
    acc0[0]  += w0 * v0.x; acc1[0]  += w1 * v0.x;
    acc0[1]  += w0 * v0.y; acc1[1]  += w1 * v0.y;
    acc0[2]  += w0 * v0.z; acc1[2]  += w1 * v0.z;
    acc0[3]  += w0 * v0.w; acc1[3]  += w1 * v0.w;
    acc0[4]  += w0 * v1.x; acc1[4]  += w1 * v1.x;
    acc0[5]  += w0 * v1.y; acc1[5]  += w1 * v1.y;
    acc0[6]  += w0 * v1.z; acc1[6]  += w1 * v1.z;
    acc0[7]  += w0 * v1.w; acc1[7]  += w1 * v1.w;
    acc0[8]  += w0 * v2.x; acc1[8]  += w1 * v2.x;
    acc0[9]  += w0 * v2.y; acc1[9]  += w1 * v2.y;
    acc0[10] += w0 * v2.z; acc1[10] += w1 * v2.z;
    acc0[11] += w0 * v2.w; acc1[11] += w1 * v2.w;
    acc0[12] += w0 * v3.x; acc1[12] += w1 * v3.x;
    acc0[13] += w0 * v3.y; acc1[13] += w1 * v3.y;
    acc0[14] += w0 * v3.z; acc1[14] += w1 * v3.z;
    acc0[15] += w0 * v3.w; acc1[15] += w1 * v3.w;
  }

#pragma unroll
  for (int l = 0; l < LCH; ++l) {
    part[(g4 * LCH + l) * NYOUT + i]      = acc0[l];
    part[(g4 * LCH + l) * NYOUT + 32 + i] = acc1[l];
  }
  __syncthreads();

  int y  = j & 63;
  int th = j >> 6;
  float bias = bx2y[y];
#pragma unroll
  for (int l8 = 0; l8 < 8; ++l8) {
    int l = th * 8 + l8;
    float v = part[(0 * LCH + l) * NYOUT + y]
            + part[(1 * LCH + l) * NYOUT + y]
            + part[(2 * LCH + l) * NYOUT + y]
            + part[(3 * LCH + l) * NYOUT + y] + bias;
    out[((size_t)(c * LCH + l) * NBAT + b) * NYOUT + y] = v;
  }
}

// ---------------------------------------------------------------------------
extern "C" void kernel_launch(void* const* d_in, const int* in_sizes, int n_in,
                              void* d_out, int out_size, void* d_ws, size_t ws_size,
                              hipStream_t stream) {
  (void)in_sizes; (void)n_in; (void)out_size; (void)ws_size;
  const float* y0   = (const float*)d_in[0];
  const float* U    = (const float*)d_in[1];
  const float* lrc  = (const float*)d_in[2];
  const float* lic  = (const float*)d_in[3];
  const float* Bm   = (const float*)d_in[4];
  const float* Wy2x = (const float*)d_in[5];
  const float* by2x = (const float*)d_in[6];
  const float* Wx2y = (const float*)d_in[7];
  const float* bx2y = (const float*)d_in[8];
  float* out = (float*)d_out;
  float* ws  = (float*)d_ws;   // needs >= 84.2 MB

  k_prep<<<dim3(NBAT + 2), 256, 0, stream>>>(y0, lrc, lic, Bm, Wy2x, by2x, Wx2y, ws);
  k_phaseA<<<dim3(CCH, NBAT), 128, 0, stream>>>(U, ws);
  k_phaseB<<<dim3(NBAT), 128, 0, stream>>>(ws);
  k_phaseC<<<dim3(CCH, NBAT), 128, 0, stream>>>(bx2y, out, ws);
}

// Round 2
// 164.700 us; speedup vs baseline: 1.5901x; 1.5901x over previous
//
#include <hip/hip_runtime.h>
#include <stdint.h>

// Problem dims
#define T_HRZ 1024
#define NBAT  128
#define NHID  256
#define NPAIR 128
#define NUIN  64
#define NYOUT 64
#define LCH   16   // chunk length
#define CCH   64   // number of chunks

// Workspace layout (float offsets). Total ~21.0M floats = 84.1 MB.
#define WS_LAM   0         // lr[128], li[128]
#define WS_LAML  256       // lambda^16 r[128], i[128]
#define WS_LPOW  512       // lambda^(l+1) [l][j] float2 : 16*128*2
#define WS_X0P   4608      // x0 pair-interleaved [b][j][2]
#define WS_WBU   37376     // bf16 B-frags for Bu GEMM [nt16][kk2][lane64][j8]
#define WS_WBY   45568     // bf16 B-frags for Y GEMM  [nt4][kk8][lane64][j8]
#define WS_S     53760     // chunk sums [c][b][j] float2
#define WS_E     2150912   // entry states [c][b][j] float2
#define WS_P     4248064   // within-chunk prefix, packed bf16 pairs u32 [t][b][j]

typedef __attribute__((ext_vector_type(8))) short short8;
typedef __attribute__((ext_vector_type(4))) float float4v;

__device__ __forceinline__ unsigned int f2bf_bits(float x) {
  unsigned int u = __float_as_uint(x);
  return (u + 0x7fffu + ((u >> 16) & 1u)) >> 16;  // RNE
}

// ---------------------------------------------------------------------------
// K1: prep. grid (NBAT+3) x 256.
//  blocks 0..127 : x0[b] = y0[b] @ W_y2x^T + b_y2x (pair-interleaved)
//  block 128     : lambda, lambda powers 1..16 (LPOW), lambda^16 (LAML)
//  block 129     : WBU bf16 fragment layout of BnfT[u][h] = B[h][u]*nf[h]
//  block 130     : WBY bf16 fragment layout of WT[h][y]   = W_x2y[y][h]
// ---------------------------------------------------------------------------
__global__ __launch_bounds__(256) void k_prep(
    const float* __restrict__ y0, const float* __restrict__ lrc,
    const float* __restrict__ lic, const float* __restrict__ Bm,
    const float* __restrict__ Wy2x, const float* __restrict__ by2x,
    const float* __restrict__ Wx2y, float* __restrict__ ws)
{
  int blk = blockIdx.x;
  int h = threadIdx.x;  // 0..255
  if (blk < NBAT) {
    __shared__ float y0s[NYOUT];
    if (h < NYOUT) y0s[h] = y0[blk * NYOUT + h];
    __syncthreads();
    float acc = by2x[h];
    const float* wr = Wy2x + h * NYOUT;
#pragma unroll 16
    for (int k = 0; k < NYOUT; ++k) acc += y0s[k] * wr[k];
    int j = h & (NPAIR - 1);
    int comp = h >> 7;
    ws[WS_X0P + (blk * NPAIR + j) * 2 + comp] = acc;
  } else if (blk == NBAT) {
    if (h < NPAIR) {
      float a  = fabsf(lrc[h]);
      float r  = expf(-a);
      float th = 1.5707963267948966f * lic[h];
      float lr = r * cosf(th);
      float li = r * sinf(th);
      ws[WS_LAM + h]         = lr;
      ws[WS_LAM + NPAIR + h] = li;
      float2* lp = (float2*)(ws + WS_LPOW);
      float pr = lr, pi_ = li;             // lambda^1
      lp[0 * NPAIR + h] = make_float2(pr, pi_);
      for (int l = 1; l < LCH; ++l) {
        float nr = pr * lr - pi_ * li;
        float ni = pr * li + pi_ * lr;
        pr = nr; pi_ = ni;
        lp[l * NPAIR + h] = make_float2(pr, pi_);
      }
      ws[WS_LAML + h]         = pr;        // lambda^16
      ws[WS_LAML + NPAIR + h] = pi_;
    }
  } else if (blk == NBAT + 1) {
    unsigned short* wbu = (unsigned short*)(ws + WS_WBU);
    for (int idx = h; idx < 16384; idx += 256) {
      int nt   = idx >> 10;
      int kk   = (idx >> 9) & 1;
      int lane = (idx >> 3) & 63;
      int jj   = idx & 7;
      int u  = kk * 32 + (lane >> 4) * 8 + jj;
      int hh = nt * 16 + (lane & 15);
      float a2 = fabsf(lrc[hh & (NPAIR - 1)]);
      float nf = sqrtf(1.f - expf(-2.f * a2));
      wbu[idx] = (unsigned short)f2bf_bits(Bm[hh * NUIN + u] * nf);
    }
  } else {
    unsigned short* wby = (unsigned short*)(ws + WS_WBY);
    for (int idx = h; idx < 16384; idx += 256) {
      int nt   = idx >> 12;
      int kk   = (idx >> 9) & 7;
      int lane = (idx >> 3) & 63;
      int jj   = idx & 7;
      int hh = kk * 32 + (lane >> 4) * 8 + jj;
      int y  = nt * 16 + (lane & 15);
      wby[idx] = (unsigned short)f2bf_bits(Wx2y[y * NHID + hh]);
    }
  }
}

// ---------------------------------------------------------------------------
// K2: phase A. grid (CCH, NBAT) x 128 (2 waves).
// Bu tile via MFMA (U bf16 direct from global, WBU frags from L2), transpose
// through LDS, prefix-scan from zero state -> store P[l] bf16 pairs + s[c].
// ---------------------------------------------------------------------------
__global__ __launch_bounds__(128) void k_phaseA(
    const float* __restrict__ U, float* __restrict__ ws)
{
  int c = blockIdx.x, b = blockIdx.y;
  int tid = threadIdx.x, wave = tid >> 6, lane = tid & 63;
  int m = lane & 15, quad = lane >> 4;
  __shared__ float X32[LCH * 260];   // pitch 260 -> 2-way conflicts only

  // A-frags: U[t=m][u = kk*32 + quad*8 + j]
  const float* urow = U + ((size_t)(c * LCH + m) * NBAT + b) * NUIN;
  short8 afr[2];
#pragma unroll
  for (int kk = 0; kk < 2; ++kk) {
    int u0 = kk * 32 + quad * 8;
    float4 va = *(const float4*)(urow + u0);
    float4 vb = *(const float4*)(urow + u0 + 4);
    short8 f;
    f[0] = (short)f2bf_bits(va.x); f[1] = (short)f2bf_bits(va.y);
    f[2] = (short)f2bf_bits(va.z); f[3] = (short)f2bf_bits(va.w);
    f[4] = (short)f2bf_bits(vb.x); f[5] = (short)f2bf_bits(vb.y);
    f[6] = (short)f2bf_bits(vb.z); f[7] = (short)f2bf_bits(vb.w);
    afr[kk] = f;
  }

  const short8* wbu = (const short8*)(ws + WS_WBU);
  float4v z = {0.f, 0.f, 0.f, 0.f};
  float4v acc[8];
#pragma unroll
  for (int n = 0; n < 8; ++n) acc[n] = z;
#pragma unroll
  for (int n = 0; n < 8; ++n) {
    int nt = wave * 8 + n;
    acc[n] = __builtin_amdgcn_mfma_f32_16x16x32_bf16(afr[0], wbu[(nt * 2 + 0) * 64 + lane], acc[n], 0, 0, 0);
    acc[n] = __builtin_amdgcn_mfma_f32_16x16x32_bf16(afr[1], wbu[(nt * 2 + 1) * 64 + lane], acc[n], 0, 0, 0);
  }

  // C-layout (row=quad*4+r = t, col=lane&15) -> LDS [t][h]
#pragma unroll
  for (int n = 0; n < 8; ++n) {
    int hh = (wave * 8 + n) * 16 + (lane & 15);
#pragma unroll
    for (int r = 0; r < 4; ++r)
      X32[(quad * 4 + r) * 260 + hh] = acc[n][r];
  }
  __syncthreads();

  int j = tid;
  float lr = ws[WS_LAM + j], li = ws[WS_LAM + NPAIR + j];
  float s1 = 0.f, s2 = 0.f;
  unsigned int* P = (unsigned int*)(ws + WS_P);
#pragma unroll
  for (int l = 0; l < LCH; ++l) {
    float v1 = X32[l * 260 + j];
    float v2 = X32[l * 260 + NPAIR + j];
    float n1 = lr * s1 - li * s2 + v1;
    float n2 = li * s1 + lr * s2 + v2;
    s1 = n1; s2 = n2;
    P[((size_t)(c * LCH + l) * NBAT + b) * NPAIR + j] =
        f2bf_bits(s1) | (f2bf_bits(s2) << 16);
  }
  ((float2*)(ws + WS_S))[((size_t)c * NBAT + b) * NPAIR + j] = make_float2(s1, s2);
}

// ---------------------------------------------------------------------------
// K3: phase B. grid NBAT x 128. 64-step chunk scan, 8-way prefetch.
// ---------------------------------------------------------------------------
__global__ __launch_bounds__(128) void k_phaseB(float* __restrict__ ws)
{
  int b = blockIdx.x, j = threadIdx.x;
  float e1 = ws[WS_X0P + (b * NPAIR + j) * 2 + 0];
  float e2 = ws[WS_X0P + (b * NPAIR + j) * 2 + 1];
  float Lr = ws[WS_LAML + j], Li = ws[WS_LAML + NPAIR + j];
  const float2* sp = (const float2*)(ws + WS_S);
  float2* ep = (float2*)(ws + WS_E);
  const size_t cs = (size_t)NBAT * NPAIR;
  size_t o0 = (size_t)b * NPAIR + j;
  float2 buf[8];
#pragma unroll
  for (int k = 0; k < 8; ++k) buf[k] = sp[k * cs + o0];
  for (int g = 0; g < 8; ++g) {
    float2 nxt[8];
    if (g < 7) {
#pragma unroll
      for (int k = 0; k < 8; ++k) nxt[k] = sp[(size_t)((g + 1) * 8 + k) * cs + o0];
    }
#pragma unroll
    for (int k = 0; k < 8; ++k) {
      ep[(size_t)(g * 8 + k) * cs + o0] = make_float2(e1, e2);
      float n1 = Lr * e1 - Li * e2 + buf[k].x;
      float n2 = Li * e1 + Lr * e2 + buf[k].y;
      e1 = n1; e2 = n2;
    }
    if (g < 7) {
#pragma unroll
      for (int k = 0; k < 8; ++k) buf[k] = nxt[k];
    }
  }
}

// ---------------------------------------------------------------------------
// K4: phase C. grid (CCH, NBAT) x 128 (2 waves).
// X[l] = lambda^(l+1)*e + P[l] (independent per l), bf16 into A-frag-ordered
// LDS, MFMA Y-GEMM, bias epilogue.
// ---------------------------------------------------------------------------
__global__ __launch_bounds__(128) void k_phaseC(
    const float* __restrict__ bx2y, float* __restrict__ out,
    float* __restrict__ ws)
{
  int c = blockIdx.x, b = blockIdx.y;
  int tid = threadIdx.x, wave = tid >> 6, lane = tid & 63;
  __shared__ unsigned short XA[8 * 64 * 8];  // [kk][lane][j] = X[t=lane&15][h=kk*32+(lane>>4)*8+j]

  int j = tid;
  float2 e = ((const float2*)(ws + WS_E))[((size_t)c * NBAT + b) * NPAIR + j];
  const float2* lp = (const float2*)(ws + WS_LPOW);
  const unsigned int* P = (const unsigned int*)(ws + WS_P);
  int h1 = j, h2 = j + NPAIR;
  int base1 = ((h1 >> 5) << 9) + (((h1 >> 3) & 3) << 7) + (h1 & 7);
  int base2 = ((h2 >> 5) << 9) + (((h2 >> 3) & 3) << 7) + (h2 & 7);
#pragma unroll
  for (int l = 0; l < LCH; ++l) {
    float2 lpv = lp[l * NPAIR + j];
    unsigned int pk = P[((size_t)(c * LCH + l) * NBAT + b) * NPAIR + j];
    float b1 = __uint_as_float(pk << 16);
    float b2 = __uint_as_float(pk & 0xffff0000u);
    float x1 = lpv.x * e.x - lpv.y * e.y + b1;
    float x2 = lpv.y * e.x + lpv.x * e.y + b2;
    XA[base1 + l * 8] = (unsigned short)f2bf_bits(x1);
    XA[base2 + l * 8] = (unsigned short)f2bf_bits(x2);
  }
  __syncthreads();

  const short8* xa = (const short8*)XA;
  const short8* wby = (const short8*)(ws + WS_WBY);
  float4v z = {0.f, 0.f, 0.f, 0.f};
  float4v acc0 = z, acc1 = z;
  int nt0 = wave * 2, nt1 = nt0 + 1;
#pragma unroll
  for (int kk = 0; kk < 8; ++kk) {
    short8 a = xa[kk * 64 + lane];
    acc0 = __builtin_amdgcn_mfma_f32_16x16x32_bf16(a, wby[(nt0 * 8 + kk) * 64 + lane], acc0, 0, 0, 0);
    acc1 = __builtin_amdgcn_mfma_f32_16x16x32_bf16(a, wby[(nt1 * 8 + kk) * 64 + lane], acc1, 0, 0, 0);
  }

  int col = lane & 15, quad = lane >> 4;
  float bias0 = bx2y[nt0 * 16 + col];
  float bias1 = bx2y[nt1 * 16 + col];
#pragma unroll
  for (int r = 0; r < 4; ++r) {
    int row = quad * 4 + r;  // t within chunk
    size_t o = ((size_t)(c * LCH + row) * NBAT + b) * NYOUT;
    out[o + nt0 * 16 + col] = acc0[r] + bias0;
    out[o + nt1 * 16 + col] = acc1[r] + bias1;
  }
}

// ---------------------------------------------------------------------------
extern "C" void kernel_launch(void* const* d_in, const int* in_sizes, int n_in,
                              void* d_out, int out_size, void* d_ws, size_t ws_size,
                              hipStream_t stream) {
  (void)in_sizes; (void)n_in; (void)out_size; (void)ws_size;
  const float* y0   = (const float*)d_in[0];
  const float* U    = (const float*)d_in[1];
  const float* lrc  = (const float*)d_in[2];
  const float* lic  = (const float*)d_in[3];
  const float* Bm   = (const float*)d_in[4];
  const float* Wy2x = (const float*)d_in[5];
  const float* by2x = (const float*)d_in[6];
  const float* Wx2y = (const float*)d_in[7];
  const float* bx2y = (const float*)d_in[8];
  float* out = (float*)d_out;
  float* ws  = (float*)d_ws;

  k_prep<<<dim3(NBAT + 3), 256, 0, stream>>>(y0, lrc, lic, Bm, Wy2x, by2x, Wx2y, ws);
  k_phaseA<<<dim3(CCH, NBAT), 128, 0, stream>>>(U, ws);
  k_phaseB<<<dim3(NBAT), 128, 0, stream>>>(ws);
  k_phaseC<<<dim3(CCH, NBAT), 128, 0, stream>>>(bx2y, out, ws);
}